// Round 1
// baseline (729.439 us; speedup 1.0000x reference)
//
#include <hip/hip_runtime.h>
#include <hip/hip_bf16.h>

// Problem constants
#define BB 4
#define LL 1024
#define DD 768
#define HH 12
#define HD 64
#define MREL 50
#define NBIAS 101   // 2*MREL+1

#define NEG_INF (-__builtin_inff())

// Workspace layout (floats)
#define QOFF  ((size_t)0)
#define KOFF  ((size_t)3145728)          // B*H*L*HD
#define VOFF  ((size_t)6291456)
#define AOFF  ((size_t)9437184)          // attn out [B,L,768]
#define DTOFF ((size_t)12582912)         // dt[B]

// ---------------------------------------------------------------------------
// Kernel 1: per-batch dt = nanmedian(diff(patch)) with where(isfinite&>0, dt, 1)
// Exact median via O(n^2) stable rank counting in LDS (n=1023, trivial cost).
// ---------------------------------------------------------------------------
__global__ void dt_kernel(const float* __restrict__ patch, float* __restrict__ dt) {
    __shared__ float del[LL - 1];
    __shared__ int nvalid;
    __shared__ float acc;
    int b = blockIdx.x, tid = threadIdx.x;
    if (tid == 0) { nvalid = 0; acc = 0.f; }
    __syncthreads();
    int cnt = 0;
    for (int i = tid; i < LL - 1; i += 256) {
        float v = patch[b * LL + i + 1] - patch[b * LL + i];
        del[i] = v;
        if (v == v) ++cnt;  // non-NaN
    }
    atomicAdd(&nvalid, cnt);
    __syncthreads();
    int n = nvalid;
    for (int i = tid; i < LL - 1; i += 256) {
        float v = del[i];
        if (!(v == v)) continue;
        int less = 0;
        for (int j = 0; j < LL - 1; ++j) {
            float x = del[j];
            if (x == x && (x < v || (x == v && j < i))) ++less;
        }
        if (n & 1) {
            if (less == n / 2) atomicAdd(&acc, v);
        } else {
            if (less == n / 2 - 1 || less == n / 2) atomicAdd(&acc, 0.5f * v);
        }
    }
    __syncthreads();
    if (tid == 0) {
        float m = acc;
        float res = (n > 0 && m == m && fabsf(m) != __builtin_inff() && m > 0.f) ? m : 1.0f;
        dt[b] = res;
    }
}

// ---------------------------------------------------------------------------
// Kernel 2: QKV projection. C[m][n] = sum_k A[m][k]*W[n][k] + bias[n]
// A: [4096 x 768] (query), W: [2304 x 768] (in_proj_w). 64x64 tile, 4x4/thread.
// Epilogue scatters into q (scaled 1/8), k, v buffers laid out [B,H,L,64].
// ---------------------------------------------------------------------------
__global__ __launch_bounds__(256) void qkv_kernel(
    const float* __restrict__ A, const float* __restrict__ W,
    const float* __restrict__ bias,
    float* __restrict__ qb, float* __restrict__ kb, float* __restrict__ vb) {
    __shared__ float At[16][68];  // At[kk][r] (transposed for float4 reads)
    __shared__ float Wt[16][68];
    int tid = threadIdx.x;
    int tx = tid & 15, ty = tid >> 4;
    int m0 = blockIdx.x << 6, n0 = blockIdx.y << 6;
    int r = tid >> 2, c4 = (tid & 3) << 2;
    const float* aptr = A + (size_t)(m0 + r) * DD + c4;
    const float* wptr = W + (size_t)(n0 + r) * DD + c4;
    float acc[4][4] = {};
    for (int kc = 0; kc < DD; kc += 16) {
        float4 av = *(const float4*)(aptr + kc);
        float4 wv = *(const float4*)(wptr + kc);
        __syncthreads();
        At[c4 + 0][r] = av.x; At[c4 + 1][r] = av.y; At[c4 + 2][r] = av.z; At[c4 + 3][r] = av.w;
        Wt[c4 + 0][r] = wv.x; Wt[c4 + 1][r] = wv.y; Wt[c4 + 2][r] = wv.z; Wt[c4 + 3][r] = wv.w;
        __syncthreads();
#pragma unroll
        for (int kk = 0; kk < 16; ++kk) {
            float4 a = *(const float4*)&At[kk][ty << 2];
            float4 w = *(const float4*)&Wt[kk][tx << 2];
            float aa[4] = {a.x, a.y, a.z, a.w};
            float ww[4] = {w.x, w.y, w.z, w.w};
#pragma unroll
            for (int i = 0; i < 4; ++i)
#pragma unroll
                for (int j = 0; j < 4; ++j) acc[i][j] = fmaf(aa[i], ww[j], acc[i][j]);
        }
    }
    // epilogue: tile columns are 64-aligned -> single section & head per tile
    int n_base = n0 + (tx << 2);
    int sec = n_base / DD;
    int d768 = n_base - sec * DD;
    int hh = d768 >> 6;
    int ddd = d768 & 63;
    float scale = (sec == 0) ? 0.125f : 1.0f;
    float* dst = (sec == 0) ? qb : ((sec == 1) ? kb : vb);
    float4 bv = *(const float4*)&bias[n_base];
    float bb4[4] = {bv.x, bv.y, bv.z, bv.w};
    int m_base = m0 + (ty << 2);
#pragma unroll
    for (int i = 0; i < 4; ++i) {
        int m = m_base + i;
        int bidx = m >> 10, l = m & 1023;
        float4 o;
        o.x = (acc[i][0] + bb4[0]) * scale;
        o.y = (acc[i][1] + bb4[1]) * scale;
        o.z = (acc[i][2] + bb4[2]) * scale;
        o.w = (acc[i][3] + bb4[3]) * scale;
        *(float4*)&dst[(((size_t)bidx * HH + hh) * LL + l) * HD + ddd] = o;
    }
}

// ---------------------------------------------------------------------------
// Kernel 3: flash-style attention with both relative biases.
// Block = (b,h, 64 q rows). 256 threads, 4x4 register tiles for S and O.
// ---------------------------------------------------------------------------
__global__ __launch_bounds__(256) void attn_kernel(
    const float* __restrict__ qb, const float* __restrict__ kb,
    const float* __restrict__ vb, const float* __restrict__ patch,
    const float* __restrict__ dtb, const float* __restrict__ relb,
    float* __restrict__ aout) {
    __shared__ float Qt[64][68];  // Qt[d][r]
    __shared__ float Kt[64][68];  // Kt[d][j]; reused as Pt[j][r] after scores
    __shared__ float Vs[64][68];  // Vs[j][d]
    __shared__ float sb[NBIAS];
    __shared__ float pis[64], pjs[64];
    int tid = threadIdx.x;
    int tx = tid & 15, ty = tid >> 4;
    int bh = blockIdx.x;
    int b = bh / HH, h = bh - b * HH;
    int q0 = blockIdx.y << 6;
    if (tid < NBIAS) sb[tid] = relb[h * NBIAS + tid];
    float inv_dt = 1.0f / dtb[b];
    const float* qp = qb + ((size_t)bh * LL + q0) * HD;
#pragma unroll
    for (int rep = 0; rep < 4; ++rep) {
        int idx = tid + (rep << 8);
        int rr = idx >> 4, d4 = (idx & 15) << 2;
        float4 v = *(const float4*)(qp + rr * HD + d4);
        Qt[d4 + 0][rr] = v.x; Qt[d4 + 1][rr] = v.y; Qt[d4 + 2][rr] = v.z; Qt[d4 + 3][rr] = v.w;
    }
    if (tid < 64) pis[tid] = patch[b * LL + q0 + tid];
    float m_i[4], l_i[4], O[4][4];
#pragma unroll
    for (int i = 0; i < 4; ++i) {
        m_i[i] = NEG_INF; l_i[i] = 0.f;
#pragma unroll
        for (int j = 0; j < 4; ++j) O[i][j] = 0.f;
    }
    int ig0 = q0 + (ty << 2);
    for (int kt = 0; kt < 16; ++kt) {
        __syncthreads();
        const float* kp = kb + ((size_t)bh * LL + (kt << 6)) * HD;
        const float* vp = vb + ((size_t)bh * LL + (kt << 6)) * HD;
#pragma unroll
        for (int rep = 0; rep < 4; ++rep) {
            int idx = tid + (rep << 8);
            int rr = idx >> 4, d4 = (idx & 15) << 2;
            float4 kv = *(const float4*)(kp + rr * HD + d4);
            Kt[d4 + 0][rr] = kv.x; Kt[d4 + 1][rr] = kv.y; Kt[d4 + 2][rr] = kv.z; Kt[d4 + 3][rr] = kv.w;
            float4 vv = *(const float4*)(vp + rr * HD + d4);
            *(float4*)&Vs[rr][d4] = vv;
        }
        if (tid < 64) pjs[tid] = patch[b * LL + (kt << 6) + tid];
        __syncthreads();
        // ---- scores: s[i][j] = q_row(ig0+i) . k_row(jg0+j)  (q pre-scaled) ----
        float s[4][4] = {};
#pragma unroll 8
        for (int d = 0; d < 64; ++d) {
            float4 qa = *(const float4*)&Qt[d][ty << 2];
            float4 ka = *(const float4*)&Kt[d][tx << 2];
            float aa[4] = {qa.x, qa.y, qa.z, qa.w};
            float kk4[4] = {ka.x, ka.y, ka.z, ka.w};
#pragma unroll
            for (int i = 0; i < 4; ++i)
#pragma unroll
                for (int j = 0; j < 4; ++j) s[i][j] = fmaf(aa[i], kk4[j], s[i][j]);
        }
        // ---- biases ----
        int jg0 = (kt << 6) + (tx << 2);
#pragma unroll
        for (int i = 0; i < 4; ++i) {
            float pi = pis[(ty << 2) + i];
            int ig = ig0 + i;
#pragma unroll
            for (int j = 0; j < 4; ++j) {
                int dp = (jg0 + j) - ig;
                dp = dp < -MREL ? -MREL : (dp > MREL ? MREL : dp);
                float rt = pi - pjs[(tx << 2) + j];
                if (!(rt == rt) || rt < -(float)MREL || rt > (float)MREL) rt = 0.f;
                float fr = rintf(rt * inv_dt);
                fr = fminf(fmaxf(fr, -(float)MREL), (float)MREL);
                s[i][j] += sb[dp + MREL] + sb[(int)fr + MREL];
            }
        }
        // ---- online softmax (row reductions across the 16 tx lanes) ----
#pragma unroll
        for (int i = 0; i < 4; ++i) {
            float mx = fmaxf(fmaxf(s[i][0], s[i][1]), fmaxf(s[i][2], s[i][3]));
            for (int off = 1; off < 16; off <<= 1) mx = fmaxf(mx, __shfl_xor(mx, off));
            float mn = fmaxf(m_i[i], mx);
            float alpha = __expf(m_i[i] - mn);
            float rs = 0.f;
#pragma unroll
            for (int j = 0; j < 4; ++j) {
                float p = __expf(s[i][j] - mn);
                s[i][j] = p;
                rs += p;
            }
            for (int off = 1; off < 16; off <<= 1) rs += __shfl_xor(rs, off);
            l_i[i] = l_i[i] * alpha + rs;
            m_i[i] = mn;
#pragma unroll
            for (int j = 0; j < 4; ++j) O[i][j] *= alpha;
        }
        __syncthreads();  // all waves done reading Kt as K
        // ---- write P into Kt as Pt[j][r] ----
#pragma unroll
        for (int i = 0; i < 4; ++i)
#pragma unroll
            for (int j = 0; j < 4; ++j) Kt[(tx << 2) + j][(ty << 2) + i] = s[i][j];
        __syncthreads();
        // ---- O += P @ V ----
#pragma unroll 8
        for (int jj = 0; jj < 64; ++jj) {
            float4 pa = *(const float4*)&Kt[jj][ty << 2];
            float4 vv = *(const float4*)&Vs[jj][tx << 2];
            float pp[4] = {pa.x, pa.y, pa.z, pa.w};
            float vv4[4] = {vv.x, vv.y, vv.z, vv.w};
#pragma unroll
            for (int i = 0; i < 4; ++i)
#pragma unroll
                for (int j = 0; j < 4; ++j) O[i][j] = fmaf(pp[i], vv4[j], O[i][j]);
        }
    }
    // epilogue: attn[b, l, h*64+d]
#pragma unroll
    for (int i = 0; i < 4; ++i) {
        float inv_l = 1.0f / l_i[i];
        float4 o;
        o.x = O[i][0] * inv_l; o.y = O[i][1] * inv_l;
        o.z = O[i][2] * inv_l; o.w = O[i][3] * inv_l;
        *(float4*)&aout[(size_t)(b * LL + ig0 + i) * DD + h * HD + (tx << 2)] = o;
    }
}

// ---------------------------------------------------------------------------
// Kernel 4: out projection. out[m][n] = sum_k attn[m][k]*Wo[n][k] + bo[n]
// ---------------------------------------------------------------------------
__global__ __launch_bounds__(256) void out_kernel(
    const float* __restrict__ A, const float* __restrict__ W,
    const float* __restrict__ bias, float* __restrict__ C) {
    __shared__ float At[16][68];
    __shared__ float Wt[16][68];
    int tid = threadIdx.x;
    int tx = tid & 15, ty = tid >> 4;
    int m0 = blockIdx.x << 6, n0 = blockIdx.y << 6;
    int r = tid >> 2, c4 = (tid & 3) << 2;
    const float* aptr = A + (size_t)(m0 + r) * DD + c4;
    const float* wptr = W + (size_t)(n0 + r) * DD + c4;
    float acc[4][4] = {};
    for (int kc = 0; kc < DD; kc += 16) {
        float4 av = *(const float4*)(aptr + kc);
        float4 wv = *(const float4*)(wptr + kc);
        __syncthreads();
        At[c4 + 0][r] = av.x; At[c4 + 1][r] = av.y; At[c4 + 2][r] = av.z; At[c4 + 3][r] = av.w;
        Wt[c4 + 0][r] = wv.x; Wt[c4 + 1][r] = wv.y; Wt[c4 + 2][r] = wv.z; Wt[c4 + 3][r] = wv.w;
        __syncthreads();
#pragma unroll
        for (int kk = 0; kk < 16; ++kk) {
            float4 a = *(const float4*)&At[kk][ty << 2];
            float4 w = *(const float4*)&Wt[kk][tx << 2];
            float aa[4] = {a.x, a.y, a.z, a.w};
            float ww[4] = {w.x, w.y, w.z, w.w};
#pragma unroll
            for (int i = 0; i < 4; ++i)
#pragma unroll
                for (int j = 0; j < 4; ++j) acc[i][j] = fmaf(aa[i], ww[j], acc[i][j]);
        }
    }
    int n_base = n0 + (tx << 2);
    float4 bv = *(const float4*)&bias[n_base];
    float bb4[4] = {bv.x, bv.y, bv.z, bv.w};
    int m_base = m0 + (ty << 2);
#pragma unroll
    for (int i = 0; i < 4; ++i) {
        float4 o;
        o.x = acc[i][0] + bb4[0];
        o.y = acc[i][1] + bb4[1];
        o.z = acc[i][2] + bb4[2];
        o.w = acc[i][3] + bb4[3];
        *(float4*)&C[(size_t)(m_base + i) * DD + n_base] = o;
    }
}

extern "C" void kernel_launch(void* const* d_in, const int* in_sizes, int n_in,
                              void* d_out, int out_size, void* d_ws, size_t ws_size,
                              hipStream_t stream) {
    const float* query    = (const float*)d_in[0];
    // d_in[1] (key) and d_in[2] (value) are ignored by the reference.
    const float* patch    = (const float*)d_in[3];
    const float* in_w     = (const float*)d_in[4];
    const float* in_b     = (const float*)d_in[5];
    const float* out_w    = (const float*)d_in[6];
    const float* out_b    = (const float*)d_in[7];
    const float* rel_bias = (const float*)d_in[8];
    float* ws  = (float*)d_ws;
    float* out = (float*)d_out;

    dt_kernel<<<BB, 256, 0, stream>>>(patch, ws + DTOFF);
    qkv_kernel<<<dim3(64, 36), 256, 0, stream>>>(query, in_w, in_b,
                                                 ws + QOFF, ws + KOFF, ws + VOFF);
    attn_kernel<<<dim3(BB * HH, LL / 64), 256, 0, stream>>>(
        ws + QOFF, ws + KOFF, ws + VOFF, patch, ws + DTOFF, rel_bias, ws + AOFF);
    out_kernel<<<dim3(64, 12), 256, 0, stream>>>(ws + AOFF, out_w, out_b, out);
}

// Round 2
// 514.275 us; speedup vs baseline: 1.4184x; 1.4184x over previous
//
#include <hip/hip_runtime.h>
#include <hip/hip_bf16.h>

// Problem constants
#define BB 4
#define LL 1024
#define DD 768
#define HH 12
#define HD 64
#define MREL 50
#define NBIAS 101   // 2*MREL+1
#define GK 768      // GEMM K (= DD)

#define NEG_INF (-__builtin_inff())

// Workspace layout (float offsets into d_ws)
#define QOFF   ((size_t)0)          // q  [B,H,L,64] fp32 (pre-scaled 1/8)
#define KOFF   ((size_t)3145728)    // k  [B,H,L,64] fp32
#define VOFF   ((size_t)6291456)    // v  [B,H,L,64] fp32
#define XBF_F  ((size_t)9437184)    // 3.15M bf16: query-bf16, later aout-bf16
#define WIBF_F ((size_t)11010048)   // in_proj_w bf16 [2304,768]
#define WOBF_F ((size_t)11894784)   // out_proj_w bf16 [768,768]
#define DTOFF  ((size_t)12189696)   // dt[B]
// total 12189700 floats = 48.76 MB

typedef __attribute__((ext_vector_type(8))) short bf16x8;
typedef __attribute__((ext_vector_type(4))) float f32x4;

__device__ __forceinline__ unsigned short f2bf(float f) {
    unsigned u = __float_as_uint(f);
    u += 0x7fffu + ((u >> 16) & 1u);   // RN-even (inputs finite)
    return (unsigned short)(u >> 16);
}

// async global->LDS, 16 bytes per lane. LDS dest = wave-uniform base + lane*16.
__device__ __forceinline__ void gload_lds16(const void* g, void* l) {
    __builtin_amdgcn_global_load_lds(
        (const __attribute__((address_space(1))) void*)g,
        (__attribute__((address_space(3))) void*)l, 16, 0, 0);
}

// ---------------------------------------------------------------------------
// fp32 -> bf16 conversion (RN). n must be multiple of 4 per thread bounds.
// ---------------------------------------------------------------------------
__global__ __launch_bounds__(256) void cvt_kernel(const float* __restrict__ src,
                                                  unsigned short* __restrict__ dst, int n) {
    int i = (blockIdx.x * 256 + threadIdx.x) * 4;
    if (i < n) {
        float4 v = *(const float4*)&src[i];
        ushort4 o;
        o.x = f2bf(v.x); o.y = f2bf(v.y); o.z = f2bf(v.z); o.w = f2bf(v.w);
        *(ushort4*)&dst[i] = o;
    }
}

// ---------------------------------------------------------------------------
// Kernel 1: per-batch dt = nanmedian(diff(patch)); where(isfinite&>0, dt, 1)
// ---------------------------------------------------------------------------
__global__ void dt_kernel(const float* __restrict__ patch, float* __restrict__ dt) {
    __shared__ float del[LL - 1];
    __shared__ int nvalid;
    __shared__ float acc;
    int b = blockIdx.x, tid = threadIdx.x;
    if (tid == 0) { nvalid = 0; acc = 0.f; }
    __syncthreads();
    int cnt = 0;
    for (int i = tid; i < LL - 1; i += 256) {
        float v = patch[b * LL + i + 1] - patch[b * LL + i];
        del[i] = v;
        if (v == v) ++cnt;
    }
    atomicAdd(&nvalid, cnt);
    __syncthreads();
    int n = nvalid;
    for (int i = tid; i < LL - 1; i += 256) {
        float v = del[i];
        if (!(v == v)) continue;
        int less = 0;
        for (int j = 0; j < LL - 1; ++j) {
            float x = del[j];
            if (x == x && (x < v || (x == v && j < i))) ++less;
        }
        if (n & 1) {
            if (less == n / 2) atomicAdd(&acc, v);
        } else {
            if (less == n / 2 - 1 || less == n / 2) atomicAdd(&acc, 0.5f * v);
        }
    }
    __syncthreads();
    if (tid == 0) {
        float m = acc;
        float res = (n > 0 && m == m && fabsf(m) != __builtin_inff() && m > 0.f) ? m : 1.0f;
        dt[b] = res;
    }
}

// ---------------------------------------------------------------------------
// bf16 MFMA GEMM core (m97 structure): 128x128 tile, BK=64, 16x16x32 MFMA.
// C[m][n] = sum_k A[m][k] * W[n][k]   (A,W bf16 row-major [*,768], fp32 acc)
// 256 thr = 4 waves (2x2 of 64x64); per wave 4x4 MFMA tiles.
// ---------------------------------------------------------------------------
#define GEMM_PROLOG()                                                          \
    __shared__ unsigned short As[128 * 64];                                    \
    __shared__ unsigned short Bs[128 * 64];                                    \
    int tid = threadIdx.x;                                                     \
    int m0 = blockIdx.x << 7, n0 = blockIdx.y << 7;                            \
    int lane = tid & 63, w = tid >> 6;                                         \
    int wm = (w >> 1) << 6, wn = (w & 1) << 6;                                 \
    int srow = tid >> 3;                                                       \
    int scol = (tid & 7) << 3;                                                 \
    const unsigned short* Ag = Ab + (size_t)(m0 + srow) * GK + scol;           \
    const unsigned short* Bg = Wb + (size_t)(n0 + srow) * GK + scol;           \
    unsigned short* Asp = As + tid * 8;                                        \
    unsigned short* Bsp = Bs + tid * 8;                                        \
    f32x4 acc[4][4];                                                           \
    _Pragma("unroll") for (int i = 0; i < 4; ++i)                              \
        _Pragma("unroll") for (int j = 0; j < 4; ++j)                          \
            acc[i][j] = (f32x4){0.f, 0.f, 0.f, 0.f};                           \
    int qd = lane >> 4;                                                        \
    int rA = wm + (lane & 15), rB = wn + (lane & 15);                          \
    for (int kc = 0; kc < GK; kc += 64) {                                      \
        __syncthreads();                                                       \
        _Pragma("unroll") for (int r = 0; r < 4; ++r) {                        \
            gload_lds16(Ag + (size_t)(r * 32) * GK + kc, Asp + r * 2048);      \
            gload_lds16(Bg + (size_t)(r * 32) * GK + kc, Bsp + r * 2048);      \
        }                                                                      \
        __syncthreads();                                                       \
        _Pragma("unroll") for (int ks = 0; ks < 2; ++ks) {                     \
            bf16x8 af[4], bfr[4];                                              \
            _Pragma("unroll") for (int t = 0; t < 4; ++t)                      \
                af[t] = *(const bf16x8*)&As[(rA + t * 16) * 64 + ks * 32 + qd * 8]; \
            _Pragma("unroll") for (int t = 0; t < 4; ++t)                      \
                bfr[t] = *(const bf16x8*)&Bs[(rB + t * 16) * 64 + ks * 32 + qd * 8]; \
            _Pragma("unroll") for (int i = 0; i < 4; ++i)                      \
                _Pragma("unroll") for (int j = 0; j < 4; ++j)                  \
                    acc[i][j] = __builtin_amdgcn_mfma_f32_16x16x32_bf16(       \
                        af[i], bfr[j], acc[i][j], 0, 0, 0);                    \
        }                                                                      \
    }                                                                          \
    int colL = lane & 15, rq = lane >> 4;

// QKV projection: scatter into q(*0.125)/k/v [B,H,L,64] fp32
__global__ __launch_bounds__(256) void qkv_gemm(
    const unsigned short* __restrict__ Ab, const unsigned short* __restrict__ Wb,
    const float* __restrict__ bias,
    float* __restrict__ qb, float* __restrict__ kb, float* __restrict__ vb) {
    GEMM_PROLOG();
    int sec = n0 / DD;                       // whole 128-tile is in one section
    float scale = (sec == 0) ? 0.125f : 1.0f;
    float* dst = (sec == 0) ? qb : ((sec == 1) ? kb : vb);
#pragma unroll
    for (int j = 0; j < 4; ++j) {
        int n = n0 + wn + j * 16 + colL;
        int d768 = n - sec * DD;
        int hh = d768 >> 6, dd = d768 & 63;
        float bn = bias[n];
#pragma unroll
        for (int i = 0; i < 4; ++i) {
            int rowb = m0 + wm + i * 16 + rq * 4;
#pragma unroll
            for (int r = 0; r < 4; ++r) {
                int m = rowb + r;
                int bidx = m >> 10, l = m & 1023;
                dst[(((size_t)bidx * HH + hh) * LL + l) * HD + dd] =
                    (acc[i][j][r] + bn) * scale;
            }
        }
    }
}

// Out projection: plain row-major fp32 store
__global__ __launch_bounds__(256) void out_gemm(
    const unsigned short* __restrict__ Ab, const unsigned short* __restrict__ Wb,
    const float* __restrict__ bias, float* __restrict__ C) {
    GEMM_PROLOG();
#pragma unroll
    for (int j = 0; j < 4; ++j) {
        int n = n0 + wn + j * 16 + colL;
        float bn = bias[n];
#pragma unroll
        for (int i = 0; i < 4; ++i) {
            int rowb = m0 + wm + i * 16 + rq * 4;
#pragma unroll
            for (int r = 0; r < 4; ++r)
                C[(size_t)(rowb + r) * DD + n] = acc[i][j][r] + bn;
        }
    }
}

// ---------------------------------------------------------------------------
// Kernel 3: flash-style attention (fp32), epilogue now writes bf16 aout.
// ---------------------------------------------------------------------------
__global__ __launch_bounds__(256) void attn_kernel(
    const float* __restrict__ qb, const float* __restrict__ kb,
    const float* __restrict__ vb, const float* __restrict__ patch,
    const float* __restrict__ dtb, const float* __restrict__ relb,
    unsigned short* __restrict__ aout) {
    __shared__ float Qt[64][68];  // Qt[d][r]
    __shared__ float Kt[64][68];  // Kt[d][j]; reused as Pt[j][r] after scores
    __shared__ float Vs[64][68];  // Vs[j][d]
    __shared__ float sb[NBIAS];
    __shared__ float pis[64], pjs[64];
    int tid = threadIdx.x;
    int tx = tid & 15, ty = tid >> 4;
    int bh = blockIdx.x;
    int b = bh / HH, h = bh - b * HH;
    int q0 = blockIdx.y << 6;
    if (tid < NBIAS) sb[tid] = relb[h * NBIAS + tid];
    float inv_dt = 1.0f / dtb[b];
    const float* qp = qb + ((size_t)bh * LL + q0) * HD;
#pragma unroll
    for (int rep = 0; rep < 4; ++rep) {
        int idx = tid + (rep << 8);
        int rr = idx >> 4, d4 = (idx & 15) << 2;
        float4 v = *(const float4*)(qp + rr * HD + d4);
        Qt[d4 + 0][rr] = v.x; Qt[d4 + 1][rr] = v.y; Qt[d4 + 2][rr] = v.z; Qt[d4 + 3][rr] = v.w;
    }
    if (tid < 64) pis[tid] = patch[b * LL + q0 + tid];
    float m_i[4], l_i[4], O[4][4];
#pragma unroll
    for (int i = 0; i < 4; ++i) {
        m_i[i] = NEG_INF; l_i[i] = 0.f;
#pragma unroll
        for (int j = 0; j < 4; ++j) O[i][j] = 0.f;
    }
    int ig0 = q0 + (ty << 2);
    for (int kt = 0; kt < 16; ++kt) {
        __syncthreads();
        const float* kp = kb + ((size_t)bh * LL + (kt << 6)) * HD;
        const float* vp = vb + ((size_t)bh * LL + (kt << 6)) * HD;
#pragma unroll
        for (int rep = 0; rep < 4; ++rep) {
            int idx = tid + (rep << 8);
            int rr = idx >> 4, d4 = (idx & 15) << 2;
            float4 kv = *(const float4*)(kp + rr * HD + d4);
            Kt[d4 + 0][rr] = kv.x; Kt[d4 + 1][rr] = kv.y; Kt[d4 + 2][rr] = kv.z; Kt[d4 + 3][rr] = kv.w;
            float4 vv = *(const float4*)(vp + rr * HD + d4);
            *(float4*)&Vs[rr][d4] = vv;
        }
        if (tid < 64) pjs[tid] = patch[b * LL + (kt << 6) + tid];
        __syncthreads();
        float s[4][4] = {};
#pragma unroll 8
        for (int d = 0; d < 64; ++d) {
            float4 qa = *(const float4*)&Qt[d][ty << 2];
            float4 ka = *(const float4*)&Kt[d][tx << 2];
            float aa[4] = {qa.x, qa.y, qa.z, qa.w};
            float kk4[4] = {ka.x, ka.y, ka.z, ka.w};
#pragma unroll
            for (int i = 0; i < 4; ++i)
#pragma unroll
                for (int j = 0; j < 4; ++j) s[i][j] = fmaf(aa[i], kk4[j], s[i][j]);
        }
        int jg0 = (kt << 6) + (tx << 2);
#pragma unroll
        for (int i = 0; i < 4; ++i) {
            float pi = pis[(ty << 2) + i];
            int ig = ig0 + i;
#pragma unroll
            for (int j = 0; j < 4; ++j) {
                int dp = (jg0 + j) - ig;
                dp = dp < -MREL ? -MREL : (dp > MREL ? MREL : dp);
                float rt = pi - pjs[(tx << 2) + j];
                if (!(rt == rt) || rt < -(float)MREL || rt > (float)MREL) rt = 0.f;
                float fr = rintf(rt * inv_dt);
                fr = fminf(fmaxf(fr, -(float)MREL), (float)MREL);
                s[i][j] += sb[dp + MREL] + sb[(int)fr + MREL];
            }
        }
#pragma unroll
        for (int i = 0; i < 4; ++i) {
            float mx = fmaxf(fmaxf(s[i][0], s[i][1]), fmaxf(s[i][2], s[i][3]));
            for (int off = 1; off < 16; off <<= 1) mx = fmaxf(mx, __shfl_xor(mx, off));
            float mn = fmaxf(m_i[i], mx);
            float alpha = __expf(m_i[i] - mn);
            float rs = 0.f;
#pragma unroll
            for (int j = 0; j < 4; ++j) {
                float p = __expf(s[i][j] - mn);
                s[i][j] = p;
                rs += p;
            }
            for (int off = 1; off < 16; off <<= 1) rs += __shfl_xor(rs, off);
            l_i[i] = l_i[i] * alpha + rs;
            m_i[i] = mn;
#pragma unroll
            for (int j = 0; j < 4; ++j) O[i][j] *= alpha;
        }
        __syncthreads();
#pragma unroll
        for (int i = 0; i < 4; ++i)
#pragma unroll
            for (int j = 0; j < 4; ++j) Kt[(tx << 2) + j][(ty << 2) + i] = s[i][j];
        __syncthreads();
#pragma unroll 8
        for (int jj = 0; jj < 64; ++jj) {
            float4 pa = *(const float4*)&Kt[jj][ty << 2];
            float4 vv = *(const float4*)&Vs[jj][tx << 2];
            float pp[4] = {pa.x, pa.y, pa.z, pa.w};
            float vv4[4] = {vv.x, vv.y, vv.z, vv.w};
#pragma unroll
            for (int i = 0; i < 4; ++i)
#pragma unroll
                for (int j = 0; j < 4; ++j) O[i][j] = fmaf(pp[i], vv4[j], O[i][j]);
        }
    }
#pragma unroll
    for (int i = 0; i < 4; ++i) {
        float inv_l = 1.0f / l_i[i];
        ushort4 o;
        o.x = f2bf(O[i][0] * inv_l); o.y = f2bf(O[i][1] * inv_l);
        o.z = f2bf(O[i][2] * inv_l); o.w = f2bf(O[i][3] * inv_l);
        *(ushort4*)&aout[(size_t)(b * LL + ig0 + i) * DD + h * HD + (tx << 2)] = o;
    }
}

extern "C" void kernel_launch(void* const* d_in, const int* in_sizes, int n_in,
                              void* d_out, int out_size, void* d_ws, size_t ws_size,
                              hipStream_t stream) {
    const float* query    = (const float*)d_in[0];
    const float* patch    = (const float*)d_in[3];
    const float* in_w     = (const float*)d_in[4];
    const float* in_b     = (const float*)d_in[5];
    const float* out_w    = (const float*)d_in[6];
    const float* out_b    = (const float*)d_in[7];
    const float* rel_bias = (const float*)d_in[8];
    float* ws  = (float*)d_ws;
    float* out = (float*)d_out;

    unsigned short* xbf  = (unsigned short*)(ws + XBF_F);   // query bf16, then aout bf16
    unsigned short* wibf = (unsigned short*)(ws + WIBF_F);
    unsigned short* wobf = (unsigned short*)(ws + WOBF_F);

    dt_kernel<<<BB, 256, 0, stream>>>(patch, ws + DTOFF);
    cvt_kernel<<<3072, 256, 0, stream>>>(query, xbf, BB * LL * DD);
    cvt_kernel<<<1728, 256, 0, stream>>>(in_w, wibf, 3 * DD * DD);
    cvt_kernel<<<576, 256, 0, stream>>>(out_w, wobf, DD * DD);
    qkv_gemm<<<dim3(32, 18), 256, 0, stream>>>(xbf, wibf, in_b,
                                               ws + QOFF, ws + KOFF, ws + VOFF);
    attn_kernel<<<dim3(BB * HH, LL / 64), 256, 0, stream>>>(
        ws + QOFF, ws + KOFF, ws + VOFF, patch, ws + DTOFF, rel_bias, xbf);
    out_gemm<<<dim3(32, 6), 256, 0, stream>>>(xbf, wobf, out_b, out);
}

// Round 3
// 355.889 us; speedup vs baseline: 2.0496x; 1.4450x over previous
//
#include <hip/hip_runtime.h>
#include <hip/hip_bf16.h>

// Problem constants
#define BB 4
#define LL 1024
#define DD 768
#define HH 12
#define HD 64
#define MREL 50
#define NBIAS 101   // 2*MREL+1
#define GK 768      // GEMM K (= DD)
#define STR 72      // attn LDS tile stride in ushorts (144 B = 9*16 -> b128-aligned)

#define NEG_INF (-__builtin_inff())

// Workspace layout (float offsets into d_ws)
#define QB_F   ((size_t)0)          // q bf16 [B,H,L,64] (pre-scaled 1/8)
#define KB_F   ((size_t)1572864)    // k bf16 [B,H,L,64]
#define VB_F   ((size_t)3145728)    // v bf16 [B,H,L,64]
#define VTB_F  ((size_t)4718592)    // v^T bf16 [B,H,64,L]
#define XBF_F  ((size_t)6291456)    // query bf16; later aout bf16 [B,L,768]
#define WIBF_F ((size_t)7864320)    // in_proj_w bf16 [2304,768]
#define WOBF_F ((size_t)8749056)    // out_proj_w bf16 [768,768]
#define DT_F   ((size_t)9043968)    // dt[B]
// total ~9.04M floats = 36.2 MB

#define NQ4  (BB*LL*DD)       // 3145728
#define NWI4 (3*DD*DD)        // 1769472

typedef __attribute__((ext_vector_type(8)))  short bf16x8;
typedef __attribute__((ext_vector_type(4)))  float f32x4;
typedef __attribute__((ext_vector_type(16))) float f32x16;

__device__ __forceinline__ unsigned short f2bf(float f) {
    unsigned u = __float_as_uint(f);
    u += 0x7fffu + ((u >> 16) & 1u);   // RN-even (finite inputs)
    return (unsigned short)(u >> 16);
}

// async global->LDS, 16 bytes per lane (LDS dest = wave-uniform base + lane*16)
__device__ __forceinline__ void gload_lds16(const void* g, void* l) {
    __builtin_amdgcn_global_load_lds(
        (const __attribute__((address_space(1))) void*)g,
        (__attribute__((address_space(3))) void*)l, 16, 0, 0);
}

// ---------------------------------------------------------------------------
// fp32 -> bf16 for query / in_proj_w / out_proj_w in ONE launch
// ---------------------------------------------------------------------------
__global__ __launch_bounds__(256) void cvt3_kernel(
    const float* __restrict__ q, const float* __restrict__ wi, const float* __restrict__ wo,
    unsigned short* __restrict__ qd_, unsigned short* __restrict__ wid,
    unsigned short* __restrict__ wod) {
    int i = (blockIdx.x * 256 + threadIdx.x) * 4;
    const float* src; unsigned short* dst; int off;
    if (i < NQ4)              { src = q;  dst = qd_; off = i; }
    else if (i < NQ4 + NWI4)  { src = wi; dst = wid; off = i - NQ4; }
    else                      { src = wo; dst = wod; off = i - NQ4 - NWI4; }
    float4 v = *(const float4*)&src[off];
    ushort4 o;
    o.x = f2bf(v.x); o.y = f2bf(v.y); o.z = f2bf(v.z); o.w = f2bf(v.w);
    *(ushort4*)&dst[off] = o;
}

// ---------------------------------------------------------------------------
// dt = nanmedian(diff(patch)) per batch; where(isfinite&>0, dt, 1)
// ---------------------------------------------------------------------------
__global__ void dt_kernel(const float* __restrict__ patch, float* __restrict__ dt) {
    __shared__ float del[LL - 1];
    __shared__ int nvalid;
    __shared__ float acc;
    int b = blockIdx.x, tid = threadIdx.x;
    if (tid == 0) { nvalid = 0; acc = 0.f; }
    __syncthreads();
    int cnt = 0;
    for (int i = tid; i < LL - 1; i += 256) {
        float v = patch[b * LL + i + 1] - patch[b * LL + i];
        del[i] = v;
        if (v == v) ++cnt;
    }
    atomicAdd(&nvalid, cnt);
    __syncthreads();
    int n = nvalid;
    for (int i = tid; i < LL - 1; i += 256) {
        float v = del[i];
        if (!(v == v)) continue;
        int less = 0;
        for (int j = 0; j < LL - 1; ++j) {
            float x = del[j];
            if (x == x && (x < v || (x == v && j < i))) ++less;
        }
        if (n & 1) {
            if (less == n / 2) atomicAdd(&acc, v);
        } else {
            if (less == n / 2 - 1 || less == n / 2) atomicAdd(&acc, 0.5f * v);
        }
    }
    __syncthreads();
    if (tid == 0) {
        float m = acc;
        float res = (n > 0 && m == m && fabsf(m) != __builtin_inff() && m > 0.f) ? m : 1.0f;
        dt[b] = res;
    }
}

// ---------------------------------------------------------------------------
// bf16 MFMA GEMM core (m97 structure): 128x128 tile, BK=64, 16x16x32 MFMA.
// ---------------------------------------------------------------------------
#define GEMM_PROLOG()                                                          \
    __shared__ unsigned short As[128 * 64];                                    \
    __shared__ unsigned short Bs[128 * 64];                                    \
    int tid = threadIdx.x;                                                     \
    int m0 = blockIdx.x << 7, n0 = blockIdx.y << 7;                            \
    int lane = tid & 63, w = tid >> 6;                                         \
    int wm = (w >> 1) << 6, wn = (w & 1) << 6;                                 \
    int srow = tid >> 3;                                                       \
    int scol = (tid & 7) << 3;                                                 \
    const unsigned short* Ag = Ab + (size_t)(m0 + srow) * GK + scol;           \
    const unsigned short* Bg = Wb + (size_t)(n0 + srow) * GK + scol;           \
    unsigned short* Asp = As + tid * 8;                                        \
    unsigned short* Bsp = Bs + tid * 8;                                        \
    f32x4 acc[4][4];                                                           \
    _Pragma("unroll") for (int i = 0; i < 4; ++i)                              \
        _Pragma("unroll") for (int j = 0; j < 4; ++j)                          \
            acc[i][j] = (f32x4){0.f, 0.f, 0.f, 0.f};                           \
    int qd_ = lane >> 4;                                                       \
    int rA = wm + (lane & 15), rB = wn + (lane & 15);                          \
    for (int kc = 0; kc < GK; kc += 64) {                                      \
        __syncthreads();                                                       \
        _Pragma("unroll") for (int r = 0; r < 4; ++r) {                        \
            gload_lds16(Ag + (size_t)(r * 32) * GK + kc, Asp + r * 2048);      \
            gload_lds16(Bg + (size_t)(r * 32) * GK + kc, Bsp + r * 2048);      \
        }                                                                      \
        __syncthreads();                                                       \
        _Pragma("unroll") for (int ks = 0; ks < 2; ++ks) {                     \
            bf16x8 af[4], bfr[4];                                              \
            _Pragma("unroll") for (int t = 0; t < 4; ++t)                      \
                af[t] = *(const bf16x8*)&As[(rA + t * 16) * 64 + ks * 32 + qd_ * 8]; \
            _Pragma("unroll") for (int t = 0; t < 4; ++t)                      \
                bfr[t] = *(const bf16x8*)&Bs[(rB + t * 16) * 64 + ks * 32 + qd_ * 8]; \
            _Pragma("unroll") for (int i = 0; i < 4; ++i)                      \
                _Pragma("unroll") for (int j = 0; j < 4; ++j)                  \
                    acc[i][j] = __builtin_amdgcn_mfma_f32_16x16x32_bf16(       \
                        af[i], bfr[j], acc[i][j], 0, 0, 0);                    \
        }                                                                      \
    }                                                                          \
    int colL = lane & 15, rq = lane >> 4;

// QKV projection -> bf16 q(*0.125)/k/v, layout [B,H,L,64]
__global__ __launch_bounds__(256) void qkv_gemm(
    const unsigned short* __restrict__ Ab, const unsigned short* __restrict__ Wb,
    const float* __restrict__ bias,
    unsigned short* __restrict__ qb, unsigned short* __restrict__ kb,
    unsigned short* __restrict__ vb) {
    GEMM_PROLOG();
    int sec = n0 / DD;                       // whole 128-tile in one section
    float scale = (sec == 0) ? 0.125f : 1.0f;
    unsigned short* dst = (sec == 0) ? qb : ((sec == 1) ? kb : vb);
#pragma unroll
    for (int j = 0; j < 4; ++j) {
        int n = n0 + wn + j * 16 + colL;
        int d768 = n - sec * DD;
        int hh = d768 >> 6, dd = d768 & 63;
        float bn = bias[n];
#pragma unroll
        for (int i = 0; i < 4; ++i) {
            int rowb = m0 + wm + i * 16 + rq * 4;
#pragma unroll
            for (int r = 0; r < 4; ++r) {
                int m = rowb + r;
                int bidx = m >> 10, l = m & 1023;
                dst[(((size_t)bidx * HH + hh) * LL + l) * HD + dd] =
                    f2bf((acc[i][j][r] + bn) * scale);
            }
        }
    }
}

// Out projection: aout bf16 [4096,768] x W^T -> fp32 out
__global__ __launch_bounds__(256) void out_gemm(
    const unsigned short* __restrict__ Ab, const unsigned short* __restrict__ Wb,
    const float* __restrict__ bias, float* __restrict__ C) {
    GEMM_PROLOG();
#pragma unroll
    for (int j = 0; j < 4; ++j) {
        int n = n0 + wn + j * 16 + colL;
        float bn = bias[n];
#pragma unroll
        for (int i = 0; i < 4; ++i) {
            int rowb = m0 + wm + i * 16 + rq * 4;
#pragma unroll
            for (int r = 0; r < 4; ++r)
                C[(size_t)(rowb + r) * DD + n] = acc[i][j][r] + bn;
        }
    }
}

// ---------------------------------------------------------------------------
// V [B,H,L,64] -> V^T [B,H,64,L]  (64x64 bf16 tiles through LDS)
// ---------------------------------------------------------------------------
__global__ __launch_bounds__(256) void vt_kernel(const unsigned short* __restrict__ VB,
                                                 unsigned short* __restrict__ VTB) {
    __shared__ unsigned short Ts[64 * STR];
    int tid = threadIdx.x;
    int bh = blockIdx.x, l0 = blockIdx.y << 6;
    int srow = tid >> 3, sc = (tid & 7) << 3;
#pragma unroll
    for (int rep = 0; rep < 2; ++rep) {
        int r = srow + rep * 32;
        bf16x8 v = *(const bf16x8*)(VB + ((size_t)bh * LL + l0 + r) * HD + sc);
        *(bf16x8*)&Ts[r * STR + sc] = v;
    }
    __syncthreads();
    int d = tid >> 2, lc = (tid & 3) << 4;
    unsigned out[8];
#pragma unroll
    for (int p = 0; p < 8; ++p) {
        unsigned lo = Ts[(lc + p * 2) * STR + d];
        unsigned hi = Ts[(lc + p * 2 + 1) * STR + d];
        out[p] = lo | (hi << 16);
    }
    unsigned short* dst = VTB + ((size_t)bh * HD + d) * LL + l0 + lc;
    *(uint4*)(dst) = *(uint4*)&out[0];
    *(uint4*)(dst + 8) = *(uint4*)&out[4];
}

// ---------------------------------------------------------------------------
// MFMA flash attention. Block = (b,h, 64 q rows), 4 waves.
// Wave w: ST tile (jt=w&1, it=w>>1) = S^T[j 32][i 32] via mfma_32x32x16
// (A = K rows j, B = Q rows i -> softmax rows i live in lane dim).
// Then O tile (it, dt=w&1) = O[i 32][d 32] += P*V.
// ---------------------------------------------------------------------------
__global__ __launch_bounds__(256) void attn_kernel(
    const unsigned short* __restrict__ QB, const unsigned short* __restrict__ KB,
    const unsigned short* __restrict__ VTB, const float* __restrict__ patch,
    const float* __restrict__ dtb, const float* __restrict__ relb,
    unsigned short* __restrict__ aout) {
    __shared__ unsigned short Ks[64 * STR];
    __shared__ unsigned short Vt[64 * STR];
    __shared__ unsigned short Ps[64 * STR];
    __shared__ float sb[NBIAS];
    __shared__ float pjs[64];
    __shared__ float pmax_s[128];
    __shared__ float psum_s[128];
    __shared__ float alpha_s[64];
    __shared__ float linv_s[64];
    int tid = threadIdx.x;
    int w = tid >> 6, lane = tid & 63, li = lane & 31, qd = lane >> 5;
    int jt = w & 1, it = w >> 1;
    int bh = blockIdx.x, b = bh / HH, h = bh - b * HH;
    int q0 = blockIdx.y << 6;
    if (tid < NBIAS) sb[tid] = relb[h * NBIAS + tid];
    float inv_dt = 1.0f / dtb[b];
    int i_loc = it * 32 + li;
    int i_abs = q0 + i_loc;
    float pi = patch[b * LL + i_abs];
    // hoisted Q B-frags (loop-invariant): B[n=i][k=d], k = qd*8 + ks*16
    bf16x8 kq[4];
    const unsigned short* qrow = QB + ((size_t)bh * LL + i_abs) * HD + qd * 8;
#pragma unroll
    for (int ks = 0; ks < 4; ++ks) kq[ks] = *(const bf16x8*)(qrow + ks * 16);
    float m_old = NEG_INF, l_run = 0.f;
    f32x16 O;
#pragma unroll
    for (int r = 0; r < 16; ++r) O[r] = 0.f;
    int srow = tid >> 3, sc = (tid & 7) << 3;
    const unsigned short* kgb = KB + (size_t)bh * LL * HD;
    const unsigned short* vgb = VTB + (size_t)bh * HD * LL;
    for (int kt = 0; kt < 16; ++kt) {
        __syncthreads();
#pragma unroll
        for (int rep = 0; rep < 2; ++rep) {
            int r = srow + rep * 32;
            bf16x8 kv = *(const bf16x8*)(kgb + (size_t)(kt * 64 + r) * HD + sc);
            *(bf16x8*)&Ks[r * STR + sc] = kv;
            bf16x8 vv = *(const bf16x8*)(vgb + (size_t)r * LL + kt * 64 + sc);
            *(bf16x8*)&Vt[r * STR + sc] = vv;
        }
        if (tid < 16) *(float4*)&pjs[tid * 4] = *(const float4*)&patch[b * LL + kt * 64 + tid * 4];
        __syncthreads();
        // ---- S^T = K . Q^T ----
        f32x16 st;
#pragma unroll
        for (int r = 0; r < 16; ++r) st[r] = 0.f;
#pragma unroll
        for (int ks = 0; ks < 4; ++ks) {
            bf16x8 ak = *(const bf16x8*)&Ks[(jt * 32 + li) * STR + ks * 16 + qd * 8];
            st = __builtin_amdgcn_mfma_f32_32x32x16_bf16(ak, kq[ks], st, 0, 0, 0);
        }
        // ---- biases + per-lane partial max (rows j in regs, col i = lane) ----
        float pm = NEG_INF;
#pragma unroll
        for (int r = 0; r < 16; ++r) {
            int jl = (r & 3) + ((r >> 2) << 3) + (qd << 2);
            int j_abs = kt * 64 + jt * 32 + jl;
            int dp = j_abs - i_abs;
            dp = dp < -MREL ? -MREL : (dp > MREL ? MREL : dp);
            float pj = pjs[jt * 32 + jl];
            float rt = pi - pj;
            if (!(rt == rt) || rt < -(float)MREL || rt > (float)MREL) rt = 0.f;
            float fr = rintf(rt * inv_dt);
            fr = fminf(fmaxf(fr, -(float)MREL), (float)MREL);
            float v = st[r] + sb[dp + MREL] + sb[(int)fr + MREL];
            st[r] = v;
            pm = fmaxf(pm, v);
        }
        pm = fmaxf(pm, __shfl_xor(pm, 32));
        if (qd == 0) pmax_s[jt * 64 + i_loc] = pm;
        __syncthreads();
        // ---- online softmax update ----
        float mt = fmaxf(pmax_s[i_loc], pmax_s[64 + i_loc]);
        float mnew = fmaxf(m_old, mt);
        float alpha = __expf(m_old - mnew);
        m_old = mnew;
        float rs = 0.f;
        unsigned short pb[16];
#pragma unroll
        for (int r = 0; r < 16; ++r) {
            float p = __expf(st[r] - mnew);
            rs += p;
            pb[r] = f2bf(p);
        }
        rs += __shfl_xor(rs, 32);
        if (qd == 0) {
            psum_s[jt * 64 + i_loc] = rs;
            if (jt == 0) alpha_s[i_loc] = alpha;
        }
        // write P (bf16, packed pairs): Ps[i][j]
#pragma unroll
        for (int pr = 0; pr < 8; ++pr) {
            int r = pr * 2;
            int jl = (r & 3) + ((r >> 2) << 3) + (qd << 2);
            unsigned u = (unsigned)pb[r] | ((unsigned)pb[r + 1] << 16);
            *(unsigned*)&Ps[i_loc * STR + jt * 32 + jl] = u;
        }
        __syncthreads();
        if (jt == 0) l_run = l_run * alpha + psum_s[i_loc] + psum_s[64 + i_loc];
        // ---- O rescale + PV ----
#pragma unroll
        for (int r = 0; r < 16; ++r) {
            int row = (r & 3) + ((r >> 2) << 3) + (qd << 2);
            O[r] *= alpha_s[it * 32 + row];
        }
#pragma unroll
        for (int ks = 0; ks < 4; ++ks) {
            bf16x8 ap = *(const bf16x8*)&Ps[i_loc * STR + ks * 16 + qd * 8];
            bf16x8 bv = *(const bf16x8*)&Vt[(jt * 32 + li) * STR + ks * 16 + qd * 8];
            O = __builtin_amdgcn_mfma_f32_32x32x16_bf16(ap, bv, O, 0, 0, 0);
        }
    }
    if (jt == 0 && qd == 0) linv_s[i_loc] = 1.0f / l_run;
    __syncthreads();
#pragma unroll
    for (int r = 0; r < 16; ++r) {
        int row = (r & 3) + ((r >> 2) << 3) + (qd << 2);
        float v = O[r] * linv_s[it * 32 + row];
        aout[(size_t)(b * LL + q0 + it * 32 + row) * DD + h * HD + jt * 32 + li] = f2bf(v);
    }
}

extern "C" void kernel_launch(void* const* d_in, const int* in_sizes, int n_in,
                              void* d_out, int out_size, void* d_ws, size_t ws_size,
                              hipStream_t stream) {
    const float* query    = (const float*)d_in[0];
    const float* patch    = (const float*)d_in[3];
    const float* in_w     = (const float*)d_in[4];
    const float* in_b     = (const float*)d_in[5];
    const float* out_w    = (const float*)d_in[6];
    const float* out_b    = (const float*)d_in[7];
    const float* rel_bias = (const float*)d_in[8];
    float* ws  = (float*)d_ws;
    float* out = (float*)d_out;

    unsigned short* qb   = (unsigned short*)(ws + QB_F);
    unsigned short* kb   = (unsigned short*)(ws + KB_F);
    unsigned short* vb   = (unsigned short*)(ws + VB_F);
    unsigned short* vtb  = (unsigned short*)(ws + VTB_F);
    unsigned short* xbf  = (unsigned short*)(ws + XBF_F);   // query bf16, then aout bf16
    unsigned short* wibf = (unsigned short*)(ws + WIBF_F);
    unsigned short* wobf = (unsigned short*)(ws + WOBF_F);

    dt_kernel<<<BB, 256, 0, stream>>>(patch, ws + DT_F);
    cvt3_kernel<<<5376, 256, 0, stream>>>(query, in_w, out_w, xbf, wibf, wobf);
    qkv_gemm<<<dim3(32, 18), 256, 0, stream>>>(xbf, wibf, in_b, qb, kb, vb);
    vt_kernel<<<dim3(BB * HH, LL / 64), 256, 0, stream>>>(vb, vtb);
    attn_kernel<<<dim3(BB * HH, LL / 64), 256, 0, stream>>>(
        qb, kb, vtb, patch, ws + DT_F, rel_bias, xbf);
    out_gemm<<<dim3(32, 6), 256, 0, stream>>>(xbf, wobf, out_b, out);
}